// Round 6
// baseline (144.777 us; speedup 1.0000x reference)
//
#include <hip/hip_runtime.h>
#include <cstdint>

// Radius NMS: B=4, C=4 (classes 1..3), N = 8192. Output: kept_coords
// [4,3,8192,2] f32 then keep [4,3,8192] f32, flat.
//
// ROUND 6: parallel-fixpoint greedy NMS. R5's kernel-split ablation proved
// phase 2 (single-wave serial tile scan) was 70 of the 71 us. Greedy NMS is
// a DAG: keep(p) <=> no earlier kept point within 3 m. Expected earlier-
// neighbors per point ~2.6 (Gaussian sigma=30m, r=3), DAG depth ~15-40 =>
// solve by block-wide monotone fixpoint iteration instead of a serial scan.
//
// One 1024-thread block per (batch,class); 12 blocks.
// Phase 1: argmax -> valid (float4 loads); stable block-scan compaction
//          into LDS xy[rank] + packed cell (cy<<8|cx). Coords/flags stay
//          in registers for the scatter.
// Phase 2a: bin ALL candidates into 56x56 grid (cell 4.2 m >= r=3, so a
//          3x3 neighborhood covers all pairs within 3 m; clamped edges are
//          monotone => sound). CSR: count -> block scan -> cursor fill.
// Phase 2b: per-point earlier-neighbor CSR (q<r, d2<=9, EXACT d2 with fp
//          contract off): count pass -> block scan -> fill pass. Expected
//          ~5.3k edges; NB_MAX=24576 (~mean+260 sigma of Poisson).
// Phase 2c: fixpoint rounds. status[p] = 2 bits {DEC,KEPT} in one LDS u32
//          word (single atomicOr => both bits atomic). Round: for each
//          undecided p: any neighbor KEPT -> suppressed(DEC); all
//          neighbors DEC&!KEPT -> KEPT|DEC; else retry. Monotone => mid-
//          round read races benign. Lowest undecided always resolves =>
//          <= M rounds; typical 15-40.
// Phase 3: scatter own kept points from registers via phase-1 rank.
//
// Numerics: fp contract OFF so dx*dx+dy*dy matches numpy (no FMA); argmax
// uses strict > (first-max tie-break like jnp.argmax). absmax=0 in R0-R5.

#define NPTS 8192
#define CAP  2304          // candidates; M ~ Binom(8192,1/4) = 2048 +/- 39 (6.5 sigma)
#define R2C  9.0f
#define GW   56            // grid cells per dim
#define NCELL (GW * GW)    // 3136
#define GORG 117.6f        // grid covers [-117.6, 117.6), clamped beyond (3.92 sigma)
#define GINV 0.23809524f   // 1/4.2
#define GMAXC 55.0f
#define NB_MAX 24576       // neighbor-edge capacity (expected ~5.3k)

__global__ __launch_bounds__(1024) void radius_nms_kernel(
    const float* __restrict__ seg,    // [4,4,8192]
    const float* __restrict__ lidar,  // [4,5,8192]
    float* __restrict__ out)          // 294912 floats
{
#pragma clang fp contract(off)
    const int bx   = blockIdx.x;   // 0..11
    const int b    = bx / 3;
    const int cls  = (bx % 3) + 1;
    const int tid  = threadIdx.x;
    const int lane = tid & 63;
    const int wv   = tid >> 6;     // 0..15

    __shared__ float2 xy[CAP];                    // 18432 B candidate coords
    __shared__ unsigned short cellOf[CAP];        //  4608 B packed (cy<<8)|cx
    __shared__ unsigned short ptCSR[CAP];         //  4608 B ranks sorted by cell
    __shared__ unsigned short ncnt[CAP];          //  4608 B earlier-nbr count
    __shared__ unsigned int   nStart[CAP];        //  9216 B nbr CSR starts
    __shared__ unsigned int   cellCnt[NCELL];     // 12544 B count / cursor
    __shared__ unsigned int   cellStart[NCELL];   // 12544 B cell CSR starts
    __shared__ unsigned short nbr[NB_MAX];        // 49152 B nbr CSR entries
    __shared__ unsigned int   statusW[CAP / 16];  //   576 B 2-bit status x16
    __shared__ int waveTot[16];
    __shared__ int remaining;
    // total ~116.4 KB LDS -> 1 block/CU

    float* out0 = out + (size_t)bx * NPTS * 2;
    float* out1 = out + 196608 + (size_t)bx * NPTS;

    // ---- zero outputs (harness poisons d_out) + init LDS ----
    const float4 z4 = make_float4(0.f, 0.f, 0.f, 0.f);
    float4* o04 = (float4*)out0;
    float4* o14 = (float4*)out1;
    for (int i = tid; i < NPTS / 2; i += 1024) o04[i] = z4;   // 16384 floats
    for (int i = tid; i < NPTS / 4; i += 1024) o14[i] = z4;   // 8192 floats
    for (int i = tid; i < NCELL; i += 1024) cellCnt[i] = 0u;
    for (int i = tid; i < CAP; i += 1024) ncnt[i] = 0;
    if (tid < CAP / 16) statusW[tid] = 0u;

    // ---- phase 1: argmax + valid flags (8 pts/thread, float4 loads) ----
    const float* segb = seg + (size_t)b * 4 * NPTS;
    const float* lx   = lidar + (size_t)b * 5 * NPTS;
    const float* ly   = lx + NPTS;

    const int n0 = tid * 8;
    const float4 a0 = *(const float4*)(segb + n0);
    const float4 a1 = *(const float4*)(segb + n0 + 4);
    const float4 b0 = *(const float4*)(segb + NPTS + n0);
    const float4 b1 = *(const float4*)(segb + NPTS + n0 + 4);
    const float4 c0 = *(const float4*)(segb + 2 * NPTS + n0);
    const float4 c1 = *(const float4*)(segb + 2 * NPTS + n0 + 4);
    const float4 d0 = *(const float4*)(segb + 3 * NPTS + n0);
    const float4 d1 = *(const float4*)(segb + 3 * NPTS + n0 + 4);
    const float4 xv0 = *(const float4*)(lx + n0);
    const float4 xv1 = *(const float4*)(lx + n0 + 4);
    const float4 yv0 = *(const float4*)(ly + n0);
    const float4 yv1 = *(const float4*)(ly + n0 + 4);

    const float v0[8] = {a0.x,a0.y,a0.z,a0.w, a1.x,a1.y,a1.z,a1.w};
    const float v1[8] = {b0.x,b0.y,b0.z,b0.w, b1.x,b1.y,b1.z,b1.w};
    const float v2[8] = {c0.x,c0.y,c0.z,c0.w, c1.x,c1.y,c1.z,c1.w};
    const float v3[8] = {d0.x,d0.y,d0.z,d0.w, d1.x,d1.y,d1.z,d1.w};
    const float px[8] = {xv0.x,xv0.y,xv0.z,xv0.w, xv1.x,xv1.y,xv1.z,xv1.w};
    const float py[8] = {yv0.x,yv0.y,yv0.z,yv0.w, yv1.x,yv1.y,yv1.z,yv1.w};

    int flags = 0, cnt = 0;
#pragma unroll
    for (int k = 0; k < 8; ++k) {
        int bi = 0; float bv = v0[k];
        if (v1[k] > bv) { bv = v1[k]; bi = 1; }
        if (v2[k] > bv) { bv = v2[k]; bi = 2; }
        if (v3[k] > bv) { bv = v3[k]; bi = 3; }
        if (bi == cls) { flags |= (1 << k); ++cnt; }
    }

    // ---- stable block scan of per-thread counts ----
    int v = cnt;
    for (int off = 1; off < 64; off <<= 1) {
        int nv = __shfl_up(v, off, 64);
        if (lane >= off) v += nv;
    }
    if (lane == 63) waveTot[wv] = v;
    __syncthreads();
    if (wv == 0) {
        int t = (lane < 16) ? waveTot[lane] : 0;
        for (int off = 1; off < 16; off <<= 1) {
            int nt = __shfl_up(t, off, 64);
            if (lane >= off) t += nt;
        }
        if (lane < 16) waveTot[lane] = t;
    }
    __syncthreads();

    int M = waveTot[15];
    if (M > CAP) M = CAP;
    const int rank0 = ((wv == 0) ? 0 : waveTot[wv - 1]) + v - cnt;
    int base = rank0;
#pragma unroll
    for (int k = 0; k < 8; ++k) {
        if (flags & (1 << k)) {
            if (base < CAP) {
                xy[base] = make_float2(px[k], py[k]);
                float fx = floorf((px[k] + GORG) * GINV);
                fx = fminf(fmaxf(fx, 0.0f), GMAXC);
                float fy = floorf((py[k] + GORG) * GINV);
                fy = fminf(fmaxf(fy, 0.0f), GMAXC);
                cellOf[base] = (unsigned short)(((int)fy << 8) | (int)fx);
            }
            ++base;
        }
    }
    __syncthreads();

    // ---- phase 2a: bin candidates into cell CSR ----
    for (int r = tid; r < M; r += 1024) {
        const int cc = cellOf[r];
        atomicAdd(&cellCnt[(cc >> 8) * GW + (cc & 255)], 1u);
    }
    __syncthreads();

    // exclusive scan of cellCnt[0..3135] -> cellStart (4 cells/thread)
    {
        const int c4 = tid * 4;
        int sa = 0, sb = 0, sc = 0, sd = 0;
        if (c4 < NCELL) {
            sa = cellCnt[c4]; sb = cellCnt[c4 + 1];
            sc = cellCnt[c4 + 2]; sd = cellCnt[c4 + 3];
        }
        int sum = sa + sb + sc + sd;
        int inc = sum;
        for (int off = 1; off < 64; off <<= 1) {
            int t = __shfl_up(inc, off, 64);
            if (lane >= off) inc += t;
        }
        if (lane == 63) waveTot[wv] = inc;
        __syncthreads();
        if (wv == 0) {
            int t = (lane < 16) ? waveTot[lane] : 0;
            for (int off = 1; off < 16; off <<= 1) {
                int u = __shfl_up(t, off, 64);
                if (lane >= off) t += u;
            }
            if (lane < 16) waveTot[lane] = t;
        }
        __syncthreads();
        const int bb = ((wv == 0) ? 0 : waveTot[wv - 1]) + inc - sum;
        if (c4 < NCELL) {
            cellStart[c4]     = bb;
            cellStart[c4 + 1] = bb + sa;
            cellStart[c4 + 2] = bb + sa + sb;
            cellStart[c4 + 3] = bb + sa + sb + sc;
        }
    }
    __syncthreads();

    // re-zero cellCnt (reuse as fill cursor)
    for (int i = tid; i < NCELL; i += 1024) cellCnt[i] = 0u;
    __syncthreads();

    for (int r = tid; r < M; r += 1024) {
        const int cc = cellOf[r];
        const int c = (cc >> 8) * GW + (cc & 255);
        const unsigned pos = cellStart[c] + atomicAdd(&cellCnt[c], 1u);
        ptCSR[pos] = (unsigned short)r;
    }
    __syncthreads();

    // ---- phase 2b: earlier-neighbor CSR (count, scan, fill) ----
    for (int r = tid; r < M; r += 1024) {
        const float2 q = xy[r];
        const int cc = cellOf[r];
        const int cx = cc & 255, cy = cc >> 8;
        const int x0 = (cx > 0) ? cx - 1 : 0, x1 = (cx < GW - 1) ? cx + 1 : GW - 1;
        const int y0 = (cy > 0) ? cy - 1 : 0, y1 = (cy < GW - 1) ? cy + 1 : GW - 1;
        int nc = 0;
        for (int yy = y0; yy <= y1; ++yy)
            for (int xx = x0; xx <= x1; ++xx) {
                const int c = yy * GW + xx;
                const unsigned s = cellStart[c], n = cellCnt[c];
                for (unsigned k = 0; k < n; ++k) {
                    const int qr = ptCSR[s + k];
                    if (qr < r) {
                        const float2 o = xy[qr];
                        const float dx = q.x - o.x, dy = q.y - o.y;
                        if (dx * dx + dy * dy <= R2C) ++nc;
                    }
                }
            }
        ncnt[r] = (unsigned short)nc;
    }
    __syncthreads();

    // exclusive scan of ncnt[0..2303] -> nStart (3 ranks/thread)
    {
        const int r3 = tid * 3;
        int sa = 0, sb = 0, sc = 0;
        if (r3 < CAP) { sa = ncnt[r3]; sb = ncnt[r3 + 1]; sc = ncnt[r3 + 2]; }
        int sum = sa + sb + sc;
        int inc = sum;
        for (int off = 1; off < 64; off <<= 1) {
            int t = __shfl_up(inc, off, 64);
            if (lane >= off) inc += t;
        }
        if (lane == 63) waveTot[wv] = inc;
        __syncthreads();
        if (wv == 0) {
            int t = (lane < 16) ? waveTot[lane] : 0;
            for (int off = 1; off < 16; off <<= 1) {
                int u = __shfl_up(t, off, 64);
                if (lane >= off) t += u;
            }
            if (lane < 16) waveTot[lane] = t;
        }
        __syncthreads();
        const int bb = ((wv == 0) ? 0 : waveTot[wv - 1]) + inc - sum;
        if (r3 < CAP) {
            nStart[r3]     = bb;
            nStart[r3 + 1] = bb + sa;
            nStart[r3 + 2] = bb + sa + sb;
        }
    }
    __syncthreads();

    for (int r = tid; r < M; r += 1024) {
        const float2 q = xy[r];
        const int cc = cellOf[r];
        const int cx = cc & 255, cy = cc >> 8;
        const int x0 = (cx > 0) ? cx - 1 : 0, x1 = (cx < GW - 1) ? cx + 1 : GW - 1;
        const int y0 = (cy > 0) ? cy - 1 : 0, y1 = (cy < GW - 1) ? cy + 1 : GW - 1;
        unsigned pos = nStart[r];
        for (int yy = y0; yy <= y1; ++yy)
            for (int xx = x0; xx <= x1; ++xx) {
                const int c = yy * GW + xx;
                const unsigned s = cellStart[c], n = cellCnt[c];
                for (unsigned k = 0; k < n; ++k) {
                    const int qr = ptCSR[s + k];
                    if (qr < r) {
                        const float2 o = xy[qr];
                        const float dx = q.x - o.x, dy = q.y - o.y;
                        if (dx * dx + dy * dy <= R2C) {
                            if (pos < NB_MAX) nbr[pos] = (unsigned short)qr;
                            ++pos;
                        }
                    }
                }
            }
    }
    __syncthreads();

    // ---- phase 2c: monotone fixpoint rounds ----
    // per-thread slots: ranks tid, tid+1024, tid+2048
    unsigned resolvedMask = 0;
    unsigned st0 = 0, en0 = 0, st1 = 0, en1 = 0, st2 = 0, en2 = 0;
    { int r = tid;        if (r < M) { st0 = nStart[r]; en0 = st0 + ncnt[r]; if (en0 > NB_MAX) en0 = NB_MAX; } else resolvedMask |= 1u; }
    { int r = tid + 1024; if (r < M) { st1 = nStart[r]; en1 = st1 + ncnt[r]; if (en1 > NB_MAX) en1 = NB_MAX; } else resolvedMask |= 2u; }
    { int r = tid + 2048; if (r < M) { st2 = nStart[r]; en2 = st2 + ncnt[r]; if (en2 > NB_MAX) en2 = NB_MAX; } else resolvedMask |= 4u; }

    auto step = [&](int r, unsigned st, unsigned en) -> int {
        bool sup = false, allDec = true;
        for (unsigned k = st; k < en; ++k) {
            const int q = nbr[k];
            const unsigned f = (statusW[q >> 4] >> ((q & 15) * 2)) & 3u;
            if (f & 2u) { sup = true; break; }   // kept earlier neighbor
            if (!(f & 1u)) allDec = false;       // undecided neighbor
        }
        if (sup)    { atomicOr(&statusW[r >> 4], 1u << ((r & 15) * 2)); return 1; }
        if (allDec) { atomicOr(&statusW[r >> 4], 3u << ((r & 15) * 2)); return 1; }
        return 0;
    };

    int rounds = 0;
    for (;;) {
        if (tid == 0) remaining = 0;
        __syncthreads();
        bool undec = false;
        if (!(resolvedMask & 1u)) { if (step(tid,        st0, en0)) resolvedMask |= 1u; else undec = true; }
        if (!(resolvedMask & 2u)) { if (step(tid + 1024, st1, en1)) resolvedMask |= 2u; else undec = true; }
        if (!(resolvedMask & 4u)) { if (step(tid + 2048, st2, en2)) resolvedMask |= 4u; else undec = true; }
        const unsigned long long bal = __ballot(undec);
        if (lane == 0 && bal) atomicAdd(&remaining, 1);
        __syncthreads();
        ++rounds;
        if (remaining == 0 || rounds > 3000) break;   // uniform exit
    }

    // ---- phase 3: scatter own kept points from registers ----
    int j = rank0;
#pragma unroll
    for (int k = 0; k < 8; ++k) {
        if (flags & (1 << k)) {
            if (j < M && ((statusW[j >> 4] >> ((j & 15) * 2)) & 2u)) {
                const int n = n0 + k;
                out0[2 * n]     = px[k];
                out0[2 * n + 1] = py[k];
                out1[n]         = 1.0f;
            }
            ++j;
        }
    }
}

extern "C" void kernel_launch(void* const* d_in, const int* in_sizes, int n_in,
                              void* d_out, int out_size, void* d_ws, size_t ws_size,
                              hipStream_t stream) {
    const float* seg   = (const float*)d_in[0];   // [4,4,64,128] f32
    const float* lidar = (const float*)d_in[1];   // [4,5,64,128] f32
    float* out = (float*)d_out;
    radius_nms_kernel<<<dim3(12), dim3(1024), 0, stream>>>(seg, lidar, out);
}